// Round 13
// baseline (789.863 us; speedup 1.0000x reference)
//
#include <hip/hip_runtime.h>
#include <cstdint>

#define UN 100000
#define NVERT 150000
#define EDIM 128
#define NNZC 640000
#define BATCHC 16384

typedef __attribute__((ext_vector_type(8))) short bf16x8;
typedef __attribute__((ext_vector_type(4))) float f32x4;
typedef uint32_t u32;
typedef unsigned short ushort_t;

// ---- static device scratch ----
__device__ float g_F1[(size_t)NVERT * EDIM];
__device__ float g_F2[(size_t)NVERT * EDIM];
__device__ float g_F3[(size_t)NVERT * EDIM];
__device__ float g_S0[(size_t)NVERT * EDIM];
__device__ float g_Z1[(size_t)NVERT * EDIM];
__device__ float g_h1[(size_t)BATCHC * 64];
__device__ ushort_t g_wb[3 * 4 * EDIM * EDIM];
__device__ ushort_t g_w1b[2 * 64 * 1024];
__device__ int   g_row_ptr[NVERT + 1];
__device__ int   g_cnt[NVERT];
__device__ int   g_col_s[NNZC];
__device__ float g_val_s[NNZC];
__device__ int   g_bsums[1024];

// ---- bf16 helpers ----
__device__ inline u32 f2bf(float f) {  // RNE
  u32 u = __float_as_uint(f);
  return (u + 0x7FFFu + ((u >> 16) & 1u)) >> 16;
}
__device__ inline void split_bf(float x, u32& hi16, float& lo) {
  u32 u = __float_as_uint(x);
  u32 hb = (u + 0x7FFFu + ((u >> 16) & 1u)) & 0xFFFF0000u;
  hi16 = hb >> 16;
  lo = x - __uint_as_float(hb);
}

// ---------------- utility ----------------
__global__ __launch_bounds__(256) void k_zero(int* __restrict__ p, int n) {
  int i = blockIdx.x * 256 + threadIdx.x;
  if (i < n) p[i] = 0;
}

// ---------------- CSR build ----------------
__global__ __launch_bounds__(256) void k_hist(const int* __restrict__ rows, int* __restrict__ cnt) {
  int i = blockIdx.x * 256 + threadIdx.x;
  if (i < NNZC) atomicAdd(&cnt[rows[i]], 1);
}

__device__ inline int wave_iscan(int v, int lane) {
#pragma unroll
  for (int off = 1; off < 64; off <<= 1) {
    int u = __shfl_up(v, off, 64);
    if (lane >= off) v += u;
  }
  return v;
}

__global__ __launch_bounds__(256) void k_scan1(const int* __restrict__ cnt, int* __restrict__ excl,
                                               int* __restrict__ bsums) {
  int t = threadIdx.x, gid = blockIdx.x * 256 + t;
  int lane = t & 63, w = t >> 6;
  int v = (gid < NVERT) ? cnt[gid] : 0;
  int s = wave_iscan(v, lane);
  __shared__ int ws4[4];
  if (lane == 63) ws4[w] = s;
  __syncthreads();
  int add = 0;
  for (int i = 0; i < w; ++i) add += ws4[i];
  if (gid < NVERT) excl[gid] = s + add - v;
  if (t == 255) bsums[blockIdx.x] = s + add;
}

__global__ __launch_bounds__(1024) void k_scan2(int* __restrict__ bsums, int nb) {
  int t = threadIdx.x;
  int lane = t & 63, w = t >> 6;
  int v = (t < nb) ? bsums[t] : 0;
  int s = wave_iscan(v, lane);
  __shared__ int ws16[16];
  if (lane == 63) ws16[w] = s;
  __syncthreads();
  int add = 0;
  for (int i = 0; i < w; ++i) add += ws16[i];
  if (t < nb) bsums[t] = s + add - v;
}

__global__ __launch_bounds__(256) void k_scan3(int* __restrict__ excl, const int* __restrict__ bsums,
                                               int* __restrict__ cursor) {
  int gid = blockIdx.x * 256 + threadIdx.x;
  if (gid < NVERT) {
    int v = excl[gid] + bsums[blockIdx.x];
    excl[gid] = v;
    cursor[gid] = v;
  }
  if (gid == 0) excl[NVERT] = NNZC;
}

__global__ __launch_bounds__(256) void k_scatter(const int* __restrict__ rows, const int* __restrict__ cols,
                                                 const float* __restrict__ vals, int* __restrict__ cursor,
                                                 int* __restrict__ col_s, float* __restrict__ val_s) {
  int i = blockIdx.x * 256 + threadIdx.x;
  if (i < NNZC) {
    int r = rows[i];
    int p = atomicAdd(&cursor[r], 1);
    col_s[p] = cols[i];
    val_s[p] = vals[i];
  }
}

// ---------------- weight hi/lo split: per layer {Whi, Wlo, IWhi, IWlo} ----------------
__global__ __launch_bounds__(256) void k_cvtW(const float* __restrict__ w, const float* __restrict__ iw,
                                              ushort_t* __restrict__ wb) {
  int i = blockIdx.x * 256 + threadIdx.x;
  if (i >= 2 * 3 * 16384) return;
  int m = i >= 3 * 16384;
  int j = i - m * 3 * 16384;
  int l = j >> 14, e = j & 16383;
  float x = m ? iw[j] : w[j];
  u32 h;
  float lo;
  split_bf(x, h, lo);
  size_t base = (size_t)l * 65536 + (size_t)m * 32768;
  wb[base + e] = (ushort_t)h;
  wb[base + 16384 + e] = (ushort_t)f2bf(lo);
}

// ---------------- t1_w hi/lo split ----------------
__global__ __launch_bounds__(256) void k_cvtW1(const float* __restrict__ w1, ushort_t* __restrict__ w1b) {
  int i = blockIdx.x * 256 + threadIdx.x;
  if (i >= 64 * 1024) return;
  u32 h;
  float lo;
  split_bf(w1[i], h, lo);
  w1b[i] = (ushort_t)h;
  w1b[65536 + i] = (ushort_t)f2bf(lo);
}

// ---------------- MFMA dual GEMM (2-pass, shared accumulator) ----------------
// pass 0: acc = X@W^T (3-product)      -> write Z1
// pass 1: acc += (X*X)@IW^T (3-product) -> write S0 = Z1 + Q
// per pass: 2 K-half phases staging {hi,lo} (32 KB); transpose epilogue via per-wave 8KB tiles.
__global__ __launch_bounds__(512, 4) void k_gemmZb(
    const float* __restrict__ Xu, const float* __restrict__ Xi, const ushort_t* __restrict__ wb,
    float* __restrict__ S0, float* __restrict__ Z1) {
  __shared__ ushort_t sw[4 * 128 * 64];  // 64 KB: first 32 KB staging; full for epilogue tiles
  int t = threadIdx.x;
  int w = t >> 6, lane = t & 63;
  int row0 = blockIdx.x * 256 + w * 32;
  int lr = lane & 15;
  int kg = lane >> 4;
  int kofs = kg * 8;

  f32x4 acc[2][8];
#pragma unroll
  for (int i = 0; i < 2; ++i)
#pragma unroll
    for (int j = 0; j < 8; ++j) acc[i][j] = (f32x4)0.f;

  union U8 { u32 u[4]; bf16x8 v; };

#pragma unroll
  for (int pass = 0; pass < 2; ++pass) {
    const ushort_t* wsrc = wb + pass * 32768;  // {Whi,Wlo} or {IWhi,IWlo}
#pragma unroll
    for (int ph = 0; ph < 2; ++ph) {
      __syncthreads();  // prior LDS reads (stage/epilogue) done before overwrite
      // stage 2 matrices' K-half: 2048 x 16B chunks / 512 threads = 4 each
#pragma unroll
      for (int i = 0; i < 4; ++i) {
        int c = i * 512 + t;
        int mat = c >> 10;
        int rem = c & 1023;
        int row = rem >> 3;
        int cb = (rem & 7) * 16;
        const ushort_t* src = wsrc + mat * 16384 + row * 128 + ph * 64 + (cb >> 1);
        float4 v = *(const float4*)src;
        *(float4*)((char*)sw + mat * 16384 + row * 128 + (cb ^ ((row & 7) << 4))) = v;
      }
      __syncthreads();

#pragma unroll
      for (int k0l = 0; k0l < 64; k0l += 32) {
        int kglob = ph * 64 + k0l + kofs;
        bf16x8 fh[2], fl[2];
#pragma unroll
        for (int rf = 0; rf < 2; ++rf) {
          int row = row0 + rf * 16 + lr;
          float xv[8];
          if (row < NVERT) {
            const float* xbase = (row < UN) ? (Xu + (size_t)row * EDIM)
                                            : (Xi + (size_t)(row - UN) * EDIM);
            const float4* xp = (const float4*)(xbase + kglob);
            float4 x0 = xp[0], x1 = xp[1];
            xv[0] = x0.x; xv[1] = x0.y; xv[2] = x0.z; xv[3] = x0.w;
            xv[4] = x1.x; xv[5] = x1.y; xv[6] = x1.z; xv[7] = x1.w;
          } else {
#pragma unroll
            for (int q = 0; q < 8; ++q) xv[q] = 0.f;
          }
          if (pass == 1) {
#pragma unroll
            for (int q = 0; q < 8; ++q) xv[q] = xv[q] * xv[q];
          }
          U8 xh, xl;
          u32 h0, h1;
          float l0, l1;
#pragma unroll
          for (int p = 0; p < 4; ++p) {
            split_bf(xv[2 * p], h0, l0);
            split_bf(xv[2 * p + 1], h1, l1);
            xh.u[p] = h0 | (h1 << 16);
            xl.u[p] = f2bf(l0) | (f2bf(l1) << 16);
          }
          fh[rf] = xh.v;
          fl[rf] = xl.v;
        }
        int cswz = (k0l * 2 + kg * 16) ^ ((lr & 7) << 4);
#pragma unroll
        for (int cf = 0; cf < 8; ++cf) {
          int rb = (cf * 16 + lr) * 128 + cswz;
          bf16x8 wh = *(const bf16x8*)((const char*)sw + rb);
          bf16x8 wl = *(const bf16x8*)((const char*)sw + 16384 + rb);
#pragma unroll
          for (int rf = 0; rf < 2; ++rf) {
            acc[rf][cf] = __builtin_amdgcn_mfma_f32_16x16x32_bf16(fh[rf], wh, acc[rf][cf], 0, 0, 0);
            acc[rf][cf] = __builtin_amdgcn_mfma_f32_16x16x32_bf16(fl[rf], wh, acc[rf][cf], 0, 0, 0);
            acc[rf][cf] = __builtin_amdgcn_mfma_f32_16x16x32_bf16(fh[rf], wl, acc[rf][cf], 0, 0, 0);
          }
        }
      }
    }

    // ---- pass epilogue: per-wave private LDS transpose -> coalesced float4 stores ----
    __syncthreads();  // all waves done reading staged weights
    char* ep = (char*)sw + w * 8192;  // 16 rows x 512 B, XOR-swizzled
    float* dst = pass ? S0 : Z1;
#pragma unroll
    for (int rf = 0; rf < 2; ++rf) {
#pragma unroll
      for (int cf = 0; cf < 8; ++cf) {
        int col = cf * 16 + lr;
#pragma unroll
        for (int r = 0; r < 4; ++r) {
          int row = kg * 4 + r;
          *(float*)(ep + row * 512 + ((col * 4) ^ ((row & 7) << 4))) = acc[rf][cf][r];
        }
      }
#pragma unroll
      for (int it = 0; it < 8; ++it) {
        int row2 = it * 2 + (lane >> 5);
        int gr = row0 + rf * 16 + row2;
        float4 v4 = *(float4*)(ep + row2 * 512 + (((lane & 31) * 16) ^ ((row2 & 7) << 4)));
        if (gr < NVERT) *(float4*)&dst[(size_t)gr * EDIM + (lane & 31) * 4] = v4;
      }
    }
  }
}

// ---------------- SpMM + epilogue: Xn = leaky(L@S0 + Z1 + b + ib) ----------------
// NT load on Z1 (read-once); NORMAL store on Xn (next layer's gemm reads it)
__global__ __launch_bounds__(256) void k_spmm2(
    const int* __restrict__ rp, const int* __restrict__ cs, const float* __restrict__ vs,
    const float* __restrict__ S0, const float* __restrict__ Z1,
    const float* __restrict__ gb, const float* __restrict__ gib,
    float* __restrict__ Xn) {
  int lane = threadIdx.x & 63;
  int row = (blockIdx.x * 4 + (threadIdx.x >> 6)) * 2 + (lane >> 5);
  if (row >= NVERT) return;
  int c4 = (lane & 31) * 4;
  int beg = rp[row], end = rp[row + 1];
  float ax = 0.f, ay = 0.f, az = 0.f, aw = 0.f;
  for (int j = beg; j < end; j += 4) {
    int lim = end - 1;
    int j1 = j + 1 <= lim ? j + 1 : lim;
    int j2 = j + 2 <= lim ? j + 2 : lim;
    int j3 = j + 3 <= lim ? j + 3 : lim;
    int c0 = cs[j], c1 = cs[j1], c2 = cs[j2], c3 = cs[j3];
    float v0 = vs[j];
    float v1 = (j + 1 <= lim) ? vs[j1] : 0.f;
    float v2 = (j + 2 <= lim) ? vs[j2] : 0.f;
    float v3 = (j + 3 <= lim) ? vs[j3] : 0.f;
    float4 g0 = *(const float4*)&S0[(size_t)c0 * EDIM + c4];
    float4 g1 = *(const float4*)&S0[(size_t)c1 * EDIM + c4];
    float4 g2 = *(const float4*)&S0[(size_t)c2 * EDIM + c4];
    float4 g3 = *(const float4*)&S0[(size_t)c3 * EDIM + c4];
    ax = fmaf(v0, g0.x, ax); ay = fmaf(v0, g0.y, ay); az = fmaf(v0, g0.z, az); aw = fmaf(v0, g0.w, aw);
    ax = fmaf(v1, g1.x, ax); ay = fmaf(v1, g1.y, ay); az = fmaf(v1, g1.z, az); aw = fmaf(v1, g1.w, aw);
    ax = fmaf(v2, g2.x, ax); ay = fmaf(v2, g2.y, ay); az = fmaf(v2, g2.z, az); aw = fmaf(v2, g2.w, aw);
    ax = fmaf(v3, g3.x, ax); ay = fmaf(v3, g3.y, ay); az = fmaf(v3, g3.z, az); aw = fmaf(v3, g3.w, aw);
  }
  f32x4 z = __builtin_nontemporal_load((const f32x4*)&Z1[(size_t)row * EDIM + c4]);
  float4 b1 = *(const float4*)&gb[c4];
  float4 b2 = *(const float4*)&gib[c4];
  float o0 = ax + z.x + b1.x + b2.x;
  float o1 = ay + z.y + b1.y + b2.y;
  float o2 = az + z.z + b1.z + b2.z;
  float o3 = aw + z.w + b1.w + b2.w;
  o0 = o0 > 0.f ? o0 : 0.01f * o0;
  o1 = o1 > 0.f ? o1 : 0.01f * o1;
  o2 = o2 > 0.f ? o2 : 0.01f * o2;
  o3 = o3 > 0.f ? o3 : 0.01f * o3;
  *(float4*)&Xn[(size_t)row * EDIM + c4] = make_float4(o0, o1, o2, o3);
}

// ---------------- final t1: h1 = gather(embd,F1..3)[u,i] @ t1_w^T + b1 ----------------
__global__ __launch_bounds__(256) void k_t1b(
    const float* __restrict__ Eu, const float* __restrict__ Ei,
    const float* __restrict__ F1, const float* __restrict__ F2, const float* __restrict__ F3,
    const int* __restrict__ ui, const int* __restrict__ ii,
    const ushort_t* __restrict__ w1b, const float* __restrict__ b1,
    float* __restrict__ h1) {
  __shared__ ushort_t sw1[2 * 64 * 128];  // 32 KB: hi block, lo block
  int t = threadIdx.x;
  int w = t >> 6, lane = t & 63;
  int b0 = blockIdx.x * 128 + w * 32;
  int lr = lane & 15, kg = lane >> 4, kofs = kg * 8;

  int uidx[2], iidx[2];
#pragma unroll
  for (int rf = 0; rf < 2; ++rf) {
    int b = b0 + rf * 16 + lr;
    uidx[rf] = ui[b];
    iidx[rf] = ii[b];
  }

  f32x4 acc[2][4];
#pragma unroll
  for (int i = 0; i < 2; ++i)
#pragma unroll
    for (int j = 0; j < 4; ++j) acc[i][j] = (f32x4)0.f;

  union U8 { u32 u[4]; bf16x8 v; };

#pragma unroll
  for (int slot = 0; slot < 8; ++slot) {
    __syncthreads();
#pragma unroll
    for (int i = 0; i < 8; ++i) {
      int c = i * 256 + t;
      int comp = c >> 10;
      int rem = c & 1023;
      int row = rem >> 4;
      int cb = (rem & 15) * 16;
      const ushort_t* src = w1b + comp * 65536 + row * 1024 + slot * 128 + (cb >> 1);
      float4 v = *(const float4*)src;
      *(float4*)((char*)sw1 + comp * 16384 + row * 256 + (cb ^ ((row & 7) << 4))) = v;
    }
    __syncthreads();

    int side = slot >> 2, layer = slot & 3;
    const float* Fl = (layer == 0) ? (side ? Ei : Eu)
                    : (layer == 1) ? F1 : (layer == 2) ? F2 : F3;
    int radd = (side && layer != 0) ? UN : 0;

#pragma unroll
    for (int kk = 0; kk < 4; ++kk) {
      bf16x8 fxh[2], fxl[2];
#pragma unroll
      for (int rf = 0; rf < 2; ++rf) {
        int ridx = (side ? iidx[rf] : uidx[rf]) + radd;
        const float4* xp = (const float4*)(Fl + (size_t)ridx * EDIM + kk * 32 + kofs);
        float4 x0 = xp[0], x1 = xp[1];
        float xv[8] = {x0.x, x0.y, x0.z, x0.w, x1.x, x1.y, x1.z, x1.w};
        U8 xh, xl;
        u32 h0, h1;
        float l0, l1;
#pragma unroll
        for (int p = 0; p < 4; ++p) {
          split_bf(xv[2 * p], h0, l0);
          split_bf(xv[2 * p + 1], h1, l1);
          xh.u[p] = h0 | (h1 << 16);
          xl.u[p] = f2bf(l0) | (f2bf(l1) << 16);
        }
        fxh[rf] = xh.v;
        fxl[rf] = xl.v;
      }
      int cbyte = (kk * 64 + kg * 16) ^ ((lr & 7) << 4);
#pragma unroll
      for (int cf = 0; cf < 4; ++cf) {
        int rb = (cf * 16 + lr) * 256 + cbyte;
        bf16x8 wh = *(const bf16x8*)((const char*)sw1 + rb);
        bf16x8 wl = *(const bf16x8*)((const char*)sw1 + 16384 + rb);
#pragma unroll
        for (int rf = 0; rf < 2; ++rf) {
          acc[rf][cf] = __builtin_amdgcn_mfma_f32_16x16x32_bf16(fxh[rf], wh, acc[rf][cf], 0, 0, 0);
          acc[rf][cf] = __builtin_amdgcn_mfma_f32_16x16x32_bf16(fxl[rf], wh, acc[rf][cf], 0, 0, 0);
          acc[rf][cf] = __builtin_amdgcn_mfma_f32_16x16x32_bf16(fxh[rf], wl, acc[rf][cf], 0, 0, 0);
        }
      }
    }
  }
#pragma unroll
  for (int rf = 0; rf < 2; ++rf) {
    int rbase = b0 + rf * 16 + ((lane >> 4) << 2);
#pragma unroll
    for (int cf = 0; cf < 4; ++cf) {
      int col = cf * 16 + lr;
      float bv = b1[col];
#pragma unroll
      for (int r = 0; r < 4; ++r) {
        h1[(size_t)(rbase + r) * 64 + col] = acc[rf][cf][r] + bv;
      }
    }
  }
}

// ---------------- fused t2 + t3 (h1 holds pre-ReLU t1 output) ----------------
__global__ __launch_bounds__(256) void k_tail(const float* __restrict__ h1, const float* __restrict__ w2,
                                              const float* __restrict__ b2, const float* __restrict__ w3,
                                              const float* __restrict__ b3, float* __restrict__ out) {
  __shared__ float w2s[32][65];
  __shared__ float w3s[32];
  int t = threadIdx.x;
  for (int i = t; i < 32 * 64; i += 256) w2s[i >> 6][i & 63] = w2[i];
  if (t < 32) w3s[t] = w3[t];
  __syncthreads();
  int b = blockIdx.x * 8 + (t >> 5);
  int j = t & 31;
  const float* hr = h1 + (size_t)b * 64;
  float acc = b2[j];
#pragma unroll 8
  for (int k = 0; k < 64; ++k) {
    float hv = fmaxf(hr[k], 0.f);
    acc = fmaf(hv, w2s[j][k], acc);
  }
  acc = fmaxf(acc, 0.f);
  float p = acc * w3s[j];
#pragma unroll
  for (int off = 16; off > 0; off >>= 1) p += __shfl_xor(p, off, 64);
  if (j == 0) out[b] = p + b3[0];
}

// ---------------- launcher ----------------
extern "C" void kernel_launch(void* const* d_in, const int* in_sizes, int n_in,
                              void* d_out, int out_size, void* d_ws, size_t ws_size,
                              hipStream_t stream) {
  const int* user_idx = (const int*)d_in[0];
  const int* item_idx = (const int*)d_in[1];
  const int* rows = (const int*)d_in[2];
  const int* cols = (const int*)d_in[3];
  const float* vals = (const float*)d_in[4];
  const float* u_embd = (const float*)d_in[5];
  const float* i_embd = (const float*)d_in[6];
  const float* gnn_w = (const float*)d_in[7];
  const float* gnn_b = (const float*)d_in[8];
  const float* gnn_iw = (const float*)d_in[9];
  const float* gnn_ib = (const float*)d_in[10];
  const float* t1_w = (const float*)d_in[11];
  const float* t1_b = (const float*)d_in[12];
  const float* t2_w = (const float*)d_in[13];
  const float* t2_b = (const float*)d_in[14];
  const float* t3_w = (const float*)d_in[15];
  const float* t3_b = (const float*)d_in[16];
  float* out = (float*)d_out;
  (void)d_ws; (void)ws_size; (void)in_sizes; (void)n_in; (void)out_size;

  float *F1, *F2, *F3, *S0, *Z1, *h1, *val_s;
  ushort_t *wb, *w1b;
  int *row_ptr, *cnt, *col_s, *bsums;
  (void)hipGetSymbolAddress((void**)&F1, HIP_SYMBOL(g_F1));
  (void)hipGetSymbolAddress((void**)&F2, HIP_SYMBOL(g_F2));
  (void)hipGetSymbolAddress((void**)&F3, HIP_SYMBOL(g_F3));
  (void)hipGetSymbolAddress((void**)&S0, HIP_SYMBOL(g_S0));
  (void)hipGetSymbolAddress((void**)&Z1, HIP_SYMBOL(g_Z1));
  (void)hipGetSymbolAddress((void**)&h1, HIP_SYMBOL(g_h1));
  (void)hipGetSymbolAddress((void**)&wb, HIP_SYMBOL(g_wb));
  (void)hipGetSymbolAddress((void**)&w1b, HIP_SYMBOL(g_w1b));
  (void)hipGetSymbolAddress((void**)&row_ptr, HIP_SYMBOL(g_row_ptr));
  (void)hipGetSymbolAddress((void**)&cnt, HIP_SYMBOL(g_cnt));
  (void)hipGetSymbolAddress((void**)&col_s, HIP_SYMBOL(g_col_s));
  (void)hipGetSymbolAddress((void**)&val_s, HIP_SYMBOL(g_val_s));
  (void)hipGetSymbolAddress((void**)&bsums, HIP_SYMBOL(g_bsums));

  int nbV = (NVERT + 255) / 256;  // 586
  k_zero<<<nbV, 256, 0, stream>>>(cnt, NVERT);
  k_hist<<<(NNZC + 255) / 256, 256, 0, stream>>>(rows, cnt);
  k_scan1<<<nbV, 256, 0, stream>>>(cnt, row_ptr, bsums);
  k_scan2<<<1, 1024, 0, stream>>>(bsums, nbV);
  k_scan3<<<nbV, 256, 0, stream>>>(row_ptr, bsums, cnt);  // cnt becomes cursor
  k_scatter<<<(NNZC + 255) / 256, 256, 0, stream>>>(rows, cols, vals, cnt, col_s, val_s);
  k_cvtW<<<(2 * 3 * 16384 + 255) / 256, 256, 0, stream>>>(gnn_w, gnn_iw, wb);
  k_cvtW1<<<(64 * 1024 + 255) / 256, 256, 0, stream>>>(t1_w, w1b);

  int nbG = (NVERT + 255) / 256;  // 586
  int nbS = (NVERT + 7) / 8;      // 18750
  float* fouts[3] = {F1, F2, F3};
  const float* cu = u_embd;
  const float* ci = i_embd;
  for (int l = 0; l < 3; ++l) {
    k_gemmZb<<<nbG, 512, 0, stream>>>(cu, ci, wb + (size_t)l * 65536, S0, Z1);
    k_spmm2<<<nbS, 256, 0, stream>>>(row_ptr, col_s, val_s, S0, Z1,
                                     gnn_b + (size_t)l * EDIM, gnn_ib + (size_t)l * EDIM, fouts[l]);
    cu = fouts[l];
    ci = fouts[l] + (size_t)UN * EDIM;
  }
  k_t1b<<<BATCHC / 128, 256, 0, stream>>>(u_embd, i_embd, F1, F2, F3,
                                          user_idx, item_idx, w1b, t1_b, h1);
  k_tail<<<BATCHC / 8, 256, 0, stream>>>(h1, t2_w, t2_b, t3_w, t3_b, out);
}

// Round 14
// 587.610 us; speedup vs baseline: 1.3442x; 1.3442x over previous
//
#include <hip/hip_runtime.h>
#include <cstdint>

#define UN 100000
#define NVERT 150000
#define EDIM 128
#define NNZC 640000
#define BATCHC 16384

typedef __attribute__((ext_vector_type(8))) short bf16x8;
typedef __attribute__((ext_vector_type(4))) float f32x4;
typedef uint32_t u32;
typedef unsigned short ushort_t;

// ---- static device scratch ----
__device__ float g_F1[(size_t)NVERT * EDIM];
__device__ float g_F2[(size_t)NVERT * EDIM];
__device__ float g_F3[(size_t)NVERT * EDIM];
__device__ float g_S0[(size_t)NVERT * EDIM];
__device__ float g_Z1[(size_t)NVERT * EDIM];
__device__ float g_h1[(size_t)BATCHC * 64];
__device__ ushort_t g_wb[3 * 4 * EDIM * EDIM];
__device__ ushort_t g_w1b[2 * 64 * 1024];
__device__ int   g_row_ptr[NVERT + 1];
__device__ int   g_cnt[NVERT];
__device__ int   g_col_s[NNZC];
__device__ float g_val_s[NNZC];
__device__ int   g_bsums[1024];

// ---- bf16 helpers ----
__device__ inline u32 f2bf(float f) {  // RNE
  u32 u = __float_as_uint(f);
  return (u + 0x7FFFu + ((u >> 16) & 1u)) >> 16;
}
__device__ inline void split_bf(float x, u32& hi16, float& lo) {
  u32 u = __float_as_uint(x);
  u32 hb = (u + 0x7FFFu + ((u >> 16) & 1u)) & 0xFFFF0000u;
  hi16 = hb >> 16;
  lo = x - __uint_as_float(hb);
}

// ---------------- utility ----------------
__global__ __launch_bounds__(256) void k_zero(int* __restrict__ p, int n) {
  int i = blockIdx.x * 256 + threadIdx.x;
  if (i < n) p[i] = 0;
}

// ---------------- CSR build ----------------
__global__ __launch_bounds__(256) void k_hist(const int* __restrict__ rows, int* __restrict__ cnt) {
  int i = blockIdx.x * 256 + threadIdx.x;
  if (i < NNZC) atomicAdd(&cnt[rows[i]], 1);
}

__device__ inline int wave_iscan(int v, int lane) {
#pragma unroll
  for (int off = 1; off < 64; off <<= 1) {
    int u = __shfl_up(v, off, 64);
    if (lane >= off) v += u;
  }
  return v;
}

__global__ __launch_bounds__(256) void k_scan1(const int* __restrict__ cnt, int* __restrict__ excl,
                                               int* __restrict__ bsums) {
  int t = threadIdx.x, gid = blockIdx.x * 256 + t;
  int lane = t & 63, w = t >> 6;
  int v = (gid < NVERT) ? cnt[gid] : 0;
  int s = wave_iscan(v, lane);
  __shared__ int ws4[4];
  if (lane == 63) ws4[w] = s;
  __syncthreads();
  int add = 0;
  for (int i = 0; i < w; ++i) add += ws4[i];
  if (gid < NVERT) excl[gid] = s + add - v;
  if (t == 255) bsums[blockIdx.x] = s + add;
}

__global__ __launch_bounds__(1024) void k_scan2(int* __restrict__ bsums, int nb) {
  int t = threadIdx.x;
  int lane = t & 63, w = t >> 6;
  int v = (t < nb) ? bsums[t] : 0;
  int s = wave_iscan(v, lane);
  __shared__ int ws16[16];
  if (lane == 63) ws16[w] = s;
  __syncthreads();
  int add = 0;
  for (int i = 0; i < w; ++i) add += ws16[i];
  if (t < nb) bsums[t] = s + add - v;
}

__global__ __launch_bounds__(256) void k_scan3(int* __restrict__ excl, const int* __restrict__ bsums,
                                               int* __restrict__ cursor) {
  int gid = blockIdx.x * 256 + threadIdx.x;
  if (gid < NVERT) {
    int v = excl[gid] + bsums[blockIdx.x];
    excl[gid] = v;
    cursor[gid] = v;
  }
  if (gid == 0) excl[NVERT] = NNZC;
}

__global__ __launch_bounds__(256) void k_scatter(const int* __restrict__ rows, const int* __restrict__ cols,
                                                 const float* __restrict__ vals, int* __restrict__ cursor,
                                                 int* __restrict__ col_s, float* __restrict__ val_s) {
  int i = blockIdx.x * 256 + threadIdx.x;
  if (i < NNZC) {
    int r = rows[i];
    int p = atomicAdd(&cursor[r], 1);
    col_s[p] = cols[i];
    val_s[p] = vals[i];
  }
}

// ---------------- weight hi/lo split: per layer {Whi, Wlo, IWhi, IWlo} ----------------
__global__ __launch_bounds__(256) void k_cvtW(const float* __restrict__ w, const float* __restrict__ iw,
                                              ushort_t* __restrict__ wb) {
  int i = blockIdx.x * 256 + threadIdx.x;
  if (i >= 2 * 3 * 16384) return;
  int m = i >= 3 * 16384;
  int j = i - m * 3 * 16384;
  int l = j >> 14, e = j & 16383;
  float x = m ? iw[j] : w[j];
  u32 h;
  float lo;
  split_bf(x, h, lo);
  size_t base = (size_t)l * 65536 + (size_t)m * 32768;
  wb[base + e] = (ushort_t)h;
  wb[base + 16384 + e] = (ushort_t)f2bf(lo);
}

// ---------------- t1_w hi/lo split ----------------
__global__ __launch_bounds__(256) void k_cvtW1(const float* __restrict__ w1, ushort_t* __restrict__ w1b) {
  int i = blockIdx.x * 256 + threadIdx.x;
  if (i >= 64 * 1024) return;
  u32 h;
  float lo;
  split_bf(w1[i], h, lo);
  w1b[i] = (ushort_t)h;
  w1b[65536 + i] = (ushort_t)f2bf(lo);
}

// ---------------- MFMA dual GEMM: Z1 = X@W^T ; S0 = Z1 + (X*X)@IW^T ----------------
// single-pass dual accumulator; weights LDS-staged (2 K-half phases);
// transpose epilogue via per-wave private 8KB swizzled tiles;
// Z1 stored NONTEMPORAL (consumer is a linear stream) so S0 keeps L3 for the gather.
__global__ __launch_bounds__(512, 2) void k_gemmZb(
    const float* __restrict__ Xu, const float* __restrict__ Xi, const ushort_t* __restrict__ wb,
    float* __restrict__ S0, float* __restrict__ Z1) {
  __shared__ ushort_t sw[4 * 128 * 64];  // 64 KB (weights; reused as 8x8KB epilogue tiles)
  int t = threadIdx.x;
  int w = t >> 6, lane = t & 63;
  int row0 = blockIdx.x * 256 + w * 32;
  int lr = lane & 15;
  int kg = lane >> 4;
  int kofs = kg * 8;

  f32x4 accZ[2][8], accQ[2][8];
#pragma unroll
  for (int i = 0; i < 2; ++i)
#pragma unroll
    for (int j = 0; j < 8; ++j) { accZ[i][j] = (f32x4)0.f; accQ[i][j] = (f32x4)0.f; }

  union U8 { u32 u[4]; bf16x8 v; };

  for (int ph = 0; ph < 2; ++ph) {
    __syncthreads();
#pragma unroll
    for (int i = 0; i < 8; ++i) {
      int c = i * 512 + t;
      int mat = c >> 10;
      int rem = c & 1023;
      int row = rem >> 3;
      int cb = (rem & 7) * 16;
      const ushort_t* src = wb + mat * 16384 + row * 128 + ph * 64 + (cb >> 1);
      float4 v = *(const float4*)src;
      int swz = cb ^ ((row & 7) << 4);
      *(float4*)((char*)sw + mat * 16384 + row * 128 + swz) = v;
    }
    __syncthreads();

#pragma unroll
    for (int k0l = 0; k0l < 64; k0l += 32) {
      int kglob = ph * 64 + k0l + kofs;
      bf16x8 fxh[2], fxl[2], fqh[2], fql[2];
#pragma unroll
      for (int rf = 0; rf < 2; ++rf) {
        int row = row0 + rf * 16 + lr;
        float xv[8];
        if (row < NVERT) {
          const float* xbase = (row < UN) ? (Xu + (size_t)row * EDIM)
                                          : (Xi + (size_t)(row - UN) * EDIM);
          const float4* xp = (const float4*)(xbase + kglob);
          float4 x0 = xp[0], x1 = xp[1];
          xv[0] = x0.x; xv[1] = x0.y; xv[2] = x0.z; xv[3] = x0.w;
          xv[4] = x1.x; xv[5] = x1.y; xv[6] = x1.z; xv[7] = x1.w;
        } else {
#pragma unroll
          for (int q = 0; q < 8; ++q) xv[q] = 0.f;
        }
        U8 xh, xl, qh, ql;
        u32 h0, h1;
        float l0, l1;
#pragma unroll
        for (int p = 0; p < 4; ++p) {
          split_bf(xv[2 * p], h0, l0);
          split_bf(xv[2 * p + 1], h1, l1);
          xh.u[p] = h0 | (h1 << 16);
          xl.u[p] = f2bf(l0) | (f2bf(l1) << 16);
          float q0 = xv[2 * p] * xv[2 * p];
          float q1 = xv[2 * p + 1] * xv[2 * p + 1];
          split_bf(q0, h0, l0);
          split_bf(q1, h1, l1);
          qh.u[p] = h0 | (h1 << 16);
          ql.u[p] = f2bf(l0) | (f2bf(l1) << 16);
        }
        fxh[rf] = xh.v; fxl[rf] = xl.v; fqh[rf] = qh.v; fql[rf] = ql.v;
      }
      int cswz = (k0l * 2 + kg * 16) ^ ((lr & 7) << 4);
#pragma unroll
      for (int cf = 0; cf < 8; ++cf) {
        int rb = (cf * 16 + lr) * 128 + cswz;
        bf16x8 wh = *(const bf16x8*)((const char*)sw + rb);
        bf16x8 wl = *(const bf16x8*)((const char*)sw + 16384 + rb);
        bf16x8 ih = *(const bf16x8*)((const char*)sw + 32768 + rb);
        bf16x8 il = *(const bf16x8*)((const char*)sw + 49152 + rb);
#pragma unroll
        for (int rf = 0; rf < 2; ++rf) {
          accZ[rf][cf] = __builtin_amdgcn_mfma_f32_16x16x32_bf16(fxh[rf], wh, accZ[rf][cf], 0, 0, 0);
          accZ[rf][cf] = __builtin_amdgcn_mfma_f32_16x16x32_bf16(fxl[rf], wh, accZ[rf][cf], 0, 0, 0);
          accZ[rf][cf] = __builtin_amdgcn_mfma_f32_16x16x32_bf16(fxh[rf], wl, accZ[rf][cf], 0, 0, 0);
          accQ[rf][cf] = __builtin_amdgcn_mfma_f32_16x16x32_bf16(fqh[rf], ih, accQ[rf][cf], 0, 0, 0);
          accQ[rf][cf] = __builtin_amdgcn_mfma_f32_16x16x32_bf16(fql[rf], ih, accQ[rf][cf], 0, 0, 0);
          accQ[rf][cf] = __builtin_amdgcn_mfma_f32_16x16x32_bf16(fqh[rf], il, accQ[rf][cf], 0, 0, 0);
        }
      }
    }
  }

  // ---- epilogue: per-wave private LDS transpose -> coalesced float4 stores ----
  __syncthreads();  // all waves done reading weights before tiles overwrite them
  char* ep = (char*)sw + w * 8192;  // 16 rows x 512 B, XOR-swizzled
#pragma unroll
  for (int rf = 0; rf < 2; ++rf) {
#pragma unroll
    for (int mat = 0; mat < 2; ++mat) {
#pragma unroll
      for (int cf = 0; cf < 8; ++cf) {
        int col = cf * 16 + lr;
#pragma unroll
        for (int r = 0; r < 4; ++r) {
          int row = kg * 4 + r;
          float v = (mat == 0) ? (accZ[rf][cf][r] + accQ[rf][cf][r]) : accZ[rf][cf][r];
          *(float*)(ep + row * 512 + ((col * 4) ^ ((row & 7) << 4))) = v;
        }
      }
#pragma unroll
      for (int it = 0; it < 8; ++it) {
        int row2 = it * 2 + (lane >> 5);
        int gr = row0 + rf * 16 + row2;
        f32x4 v4 = *(f32x4*)(ep + row2 * 512 + (((lane & 31) * 16) ^ ((row2 & 7) << 4)));
        if (gr < NVERT) {
          if (mat == 0) {
            *(f32x4*)&S0[(size_t)gr * EDIM + (lane & 31) * 4] = v4;
          } else {
            __builtin_nontemporal_store(v4, (f32x4*)&Z1[(size_t)gr * EDIM + (lane & 31) * 4]);
          }
        }
      }
    }
  }
}

// ---------------- SpMM + epilogue: Xn = leaky(L@S0 + Z1 + b + ib) ----------------
// NT load on Z1 (read-once stream); NORMAL store on Xn (next layer's gemm reads it)
__global__ __launch_bounds__(256) void k_spmm2(
    const int* __restrict__ rp, const int* __restrict__ cs, const float* __restrict__ vs,
    const float* __restrict__ S0, const float* __restrict__ Z1,
    const float* __restrict__ gb, const float* __restrict__ gib,
    float* __restrict__ Xn) {
  int lane = threadIdx.x & 63;
  int row = (blockIdx.x * 4 + (threadIdx.x >> 6)) * 2 + (lane >> 5);
  if (row >= NVERT) return;
  int c4 = (lane & 31) * 4;
  int beg = rp[row], end = rp[row + 1];
  float ax = 0.f, ay = 0.f, az = 0.f, aw = 0.f;
  for (int j = beg; j < end; j += 4) {
    int lim = end - 1;
    int j1 = j + 1 <= lim ? j + 1 : lim;
    int j2 = j + 2 <= lim ? j + 2 : lim;
    int j3 = j + 3 <= lim ? j + 3 : lim;
    int c0 = cs[j], c1 = cs[j1], c2 = cs[j2], c3 = cs[j3];
    float v0 = vs[j];
    float v1 = (j + 1 <= lim) ? vs[j1] : 0.f;
    float v2 = (j + 2 <= lim) ? vs[j2] : 0.f;
    float v3 = (j + 3 <= lim) ? vs[j3] : 0.f;
    float4 g0 = *(const float4*)&S0[(size_t)c0 * EDIM + c4];
    float4 g1 = *(const float4*)&S0[(size_t)c1 * EDIM + c4];
    float4 g2 = *(const float4*)&S0[(size_t)c2 * EDIM + c4];
    float4 g3 = *(const float4*)&S0[(size_t)c3 * EDIM + c4];
    ax = fmaf(v0, g0.x, ax); ay = fmaf(v0, g0.y, ay); az = fmaf(v0, g0.z, az); aw = fmaf(v0, g0.w, aw);
    ax = fmaf(v1, g1.x, ax); ay = fmaf(v1, g1.y, ay); az = fmaf(v1, g1.z, az); aw = fmaf(v1, g1.w, aw);
    ax = fmaf(v2, g2.x, ax); ay = fmaf(v2, g2.y, ay); az = fmaf(v2, g2.z, az); aw = fmaf(v2, g2.w, aw);
    ax = fmaf(v3, g3.x, ax); ay = fmaf(v3, g3.y, ay); az = fmaf(v3, g3.z, az); aw = fmaf(v3, g3.w, aw);
  }
  f32x4 z = __builtin_nontemporal_load((const f32x4*)&Z1[(size_t)row * EDIM + c4]);
  float4 b1 = *(const float4*)&gb[c4];
  float4 b2 = *(const float4*)&gib[c4];
  float o0 = ax + z.x + b1.x + b2.x;
  float o1 = ay + z.y + b1.y + b2.y;
  float o2 = az + z.z + b1.z + b2.z;
  float o3 = aw + z.w + b1.w + b2.w;
  o0 = o0 > 0.f ? o0 : 0.01f * o0;
  o1 = o1 > 0.f ? o1 : 0.01f * o1;
  o2 = o2 > 0.f ? o2 : 0.01f * o2;
  o3 = o3 > 0.f ? o3 : 0.01f * o3;
  *(float4*)&Xn[(size_t)row * EDIM + c4] = make_float4(o0, o1, o2, o3);
}

// ---------------- final t1: h1 = gather(embd,F1..3)[u,i] @ t1_w^T + b1 ----------------
__global__ __launch_bounds__(256) void k_t1b(
    const float* __restrict__ Eu, const float* __restrict__ Ei,
    const float* __restrict__ F1, const float* __restrict__ F2, const float* __restrict__ F3,
    const int* __restrict__ ui, const int* __restrict__ ii,
    const ushort_t* __restrict__ w1b, const float* __restrict__ b1,
    float* __restrict__ h1) {
  __shared__ ushort_t sw1[2 * 64 * 128];  // 32 KB: hi block, lo block
  int t = threadIdx.x;
  int w = t >> 6, lane = t & 63;
  int b0 = blockIdx.x * 128 + w * 32;
  int lr = lane & 15, kg = lane >> 4, kofs = kg * 8;

  int uidx[2], iidx[2];
#pragma unroll
  for (int rf = 0; rf < 2; ++rf) {
    int b = b0 + rf * 16 + lr;
    uidx[rf] = ui[b];
    iidx[rf] = ii[b];
  }

  f32x4 acc[2][4];
#pragma unroll
  for (int i = 0; i < 2; ++i)
#pragma unroll
    for (int j = 0; j < 4; ++j) acc[i][j] = (f32x4)0.f;

  union U8 { u32 u[4]; bf16x8 v; };

#pragma unroll
  for (int slot = 0; slot < 8; ++slot) {
    __syncthreads();
#pragma unroll
    for (int i = 0; i < 8; ++i) {
      int c = i * 256 + t;
      int comp = c >> 10;
      int rem = c & 1023;
      int row = rem >> 4;
      int cb = (rem & 15) * 16;
      const ushort_t* src = w1b + comp * 65536 + row * 1024 + slot * 128 + (cb >> 1);
      float4 v = *(const float4*)src;
      *(float4*)((char*)sw1 + comp * 16384 + row * 256 + (cb ^ ((row & 7) << 4))) = v;
    }
    __syncthreads();

    int side = slot >> 2, layer = slot & 3;
    const float* Fl = (layer == 0) ? (side ? Ei : Eu)
                    : (layer == 1) ? F1 : (layer == 2) ? F2 : F3;
    int radd = (side && layer != 0) ? UN : 0;

#pragma unroll
    for (int kk = 0; kk < 4; ++kk) {
      bf16x8 fxh[2], fxl[2];
#pragma unroll
      for (int rf = 0; rf < 2; ++rf) {
        int ridx = (side ? iidx[rf] : uidx[rf]) + radd;
        const float4* xp = (const float4*)(Fl + (size_t)ridx * EDIM + kk * 32 + kofs);
        float4 x0 = xp[0], x1 = xp[1];
        float xv[8] = {x0.x, x0.y, x0.z, x0.w, x1.x, x1.y, x1.z, x1.w};
        U8 xh, xl;
        u32 h0, h1;
        float l0, l1;
#pragma unroll
        for (int p = 0; p < 4; ++p) {
          split_bf(xv[2 * p], h0, l0);
          split_bf(xv[2 * p + 1], h1, l1);
          xh.u[p] = h0 | (h1 << 16);
          xl.u[p] = f2bf(l0) | (f2bf(l1) << 16);
        }
        fxh[rf] = xh.v;
        fxl[rf] = xl.v;
      }
      int cbyte = (kk * 64 + kg * 16) ^ ((lr & 7) << 4);
#pragma unroll
      for (int cf = 0; cf < 4; ++cf) {
        int rb = (cf * 16 + lr) * 256 + cbyte;
        bf16x8 wh = *(const bf16x8*)((const char*)sw1 + rb);
        bf16x8 wl = *(const bf16x8*)((const char*)sw1 + 16384 + rb);
#pragma unroll
        for (int rf = 0; rf < 2; ++rf) {
          acc[rf][cf] = __builtin_amdgcn_mfma_f32_16x16x32_bf16(fxh[rf], wh, acc[rf][cf], 0, 0, 0);
          acc[rf][cf] = __builtin_amdgcn_mfma_f32_16x16x32_bf16(fxl[rf], wh, acc[rf][cf], 0, 0, 0);
          acc[rf][cf] = __builtin_amdgcn_mfma_f32_16x16x32_bf16(fxh[rf], wl, acc[rf][cf], 0, 0, 0);
        }
      }
    }
  }
#pragma unroll
  for (int rf = 0; rf < 2; ++rf) {
    int rbase = b0 + rf * 16 + ((lane >> 4) << 2);
#pragma unroll
    for (int cf = 0; cf < 4; ++cf) {
      int col = cf * 16 + lr;
      float bv = b1[col];
#pragma unroll
      for (int r = 0; r < 4; ++r) {
        h1[(size_t)(rbase + r) * 64 + col] = acc[rf][cf][r] + bv;
      }
    }
  }
}

// ---------------- fused t2 + t3 (h1 holds pre-ReLU t1 output) ----------------
__global__ __launch_bounds__(256) void k_tail(const float* __restrict__ h1, const float* __restrict__ w2,
                                              const float* __restrict__ b2, const float* __restrict__ w3,
                                              const float* __restrict__ b3, float* __restrict__ out) {
  __shared__ float w2s[32][65];
  __shared__ float w3s[32];
  int t = threadIdx.x;
  for (int i = t; i < 32 * 64; i += 256) w2s[i >> 6][i & 63] = w2[i];
  if (t < 32) w3s[t] = w3[t];
  __syncthreads();
  int b = blockIdx.x * 8 + (t >> 5);
  int j = t & 31;
  const float* hr = h1 + (size_t)b * 64;
  float acc = b2[j];
#pragma unroll 8
  for (int k = 0; k < 64; ++k) {
    float hv = fmaxf(hr[k], 0.f);
    acc = fmaf(hv, w2s[j][k], acc);
  }
  acc = fmaxf(acc, 0.f);
  float p = acc * w3s[j];
#pragma unroll
  for (int off = 16; off > 0; off >>= 1) p += __shfl_xor(p, off, 64);
  if (j == 0) out[b] = p + b3[0];
}

// ---------------- launcher ----------------
extern "C" void kernel_launch(void* const* d_in, const int* in_sizes, int n_in,
                              void* d_out, int out_size, void* d_ws, size_t ws_size,
                              hipStream_t stream) {
  const int* user_idx = (const int*)d_in[0];
  const int* item_idx = (const int*)d_in[1];
  const int* rows = (const int*)d_in[2];
  const int* cols = (const int*)d_in[3];
  const float* vals = (const float*)d_in[4];
  const float* u_embd = (const float*)d_in[5];
  const float* i_embd = (const float*)d_in[6];
  const float* gnn_w = (const float*)d_in[7];
  const float* gnn_b = (const float*)d_in[8];
  const float* gnn_iw = (const float*)d_in[9];
  const float* gnn_ib = (const float*)d_in[10];
  const float* t1_w = (const float*)d_in[11];
  const float* t1_b = (const float*)d_in[12];
  const float* t2_w = (const float*)d_in[13];
  const float* t2_b = (const float*)d_in[14];
  const float* t3_w = (const float*)d_in[15];
  const float* t3_b = (const float*)d_in[16];
  float* out = (float*)d_out;
  (void)d_ws; (void)ws_size; (void)in_sizes; (void)n_in; (void)out_size;

  float *F1, *F2, *F3, *S0, *Z1, *h1, *val_s;
  ushort_t *wb, *w1b;
  int *row_ptr, *cnt, *col_s, *bsums;
  (void)hipGetSymbolAddress((void**)&F1, HIP_SYMBOL(g_F1));
  (void)hipGetSymbolAddress((void**)&F2, HIP_SYMBOL(g_F2));
  (void)hipGetSymbolAddress((void**)&F3, HIP_SYMBOL(g_F3));
  (void)hipGetSymbolAddress((void**)&S0, HIP_SYMBOL(g_S0));
  (void)hipGetSymbolAddress((void**)&Z1, HIP_SYMBOL(g_Z1));
  (void)hipGetSymbolAddress((void**)&h1, HIP_SYMBOL(g_h1));
  (void)hipGetSymbolAddress((void**)&wb, HIP_SYMBOL(g_wb));
  (void)hipGetSymbolAddress((void**)&w1b, HIP_SYMBOL(g_w1b));
  (void)hipGetSymbolAddress((void**)&row_ptr, HIP_SYMBOL(g_row_ptr));
  (void)hipGetSymbolAddress((void**)&cnt, HIP_SYMBOL(g_cnt));
  (void)hipGetSymbolAddress((void**)&col_s, HIP_SYMBOL(g_col_s));
  (void)hipGetSymbolAddress((void**)&val_s, HIP_SYMBOL(g_val_s));
  (void)hipGetSymbolAddress((void**)&bsums, HIP_SYMBOL(g_bsums));

  int nbV = (NVERT + 255) / 256;  // 586
  k_zero<<<nbV, 256, 0, stream>>>(cnt, NVERT);
  k_hist<<<(NNZC + 255) / 256, 256, 0, stream>>>(rows, cnt);
  k_scan1<<<nbV, 256, 0, stream>>>(cnt, row_ptr, bsums);
  k_scan2<<<1, 1024, 0, stream>>>(bsums, nbV);
  k_scan3<<<nbV, 256, 0, stream>>>(row_ptr, bsums, cnt);  // cnt becomes cursor
  k_scatter<<<(NNZC + 255) / 256, 256, 0, stream>>>(rows, cols, vals, cnt, col_s, val_s);
  k_cvtW<<<(2 * 3 * 16384 + 255) / 256, 256, 0, stream>>>(gnn_w, gnn_iw, wb);
  k_cvtW1<<<(64 * 1024 + 255) / 256, 256, 0, stream>>>(t1_w, w1b);

  int nbG = (NVERT + 255) / 256;  // 586
  int nbS = (NVERT + 7) / 8;      // 18750
  float* fouts[3] = {F1, F2, F3};
  const float* cu = u_embd;
  const float* ci = i_embd;
  for (int l = 0; l < 3; ++l) {
    k_gemmZb<<<nbG, 512, 0, stream>>>(cu, ci, wb + (size_t)l * 65536, S0, Z1);
    k_spmm2<<<nbS, 256, 0, stream>>>(row_ptr, col_s, val_s, S0, Z1,
                                     gnn_b + (size_t)l * EDIM, gnn_ib + (size_t)l * EDIM, fouts[l]);
    cu = fouts[l];
    ci = fouts[l] + (size_t)UN * EDIM;
  }
  k_t1b<<<BATCHC / 128, 256, 0, stream>>>(u_embd, i_embd, F1, F2, F3,
                                          user_idx, item_idx, w1b, t1_b, h1);
  k_tail<<<BATCHC / 8, 256, 0, stream>>>(h1, t2_w, t2_b, t3_w, t3_b, out);
}

// Round 15
// 582.060 us; speedup vs baseline: 1.3570x; 1.0095x over previous
//
#include <hip/hip_runtime.h>
#include <cstdint>

#define UN 100000
#define NVERT 150000
#define EDIM 128
#define NNZC 640000
#define BATCHC 16384

typedef __attribute__((ext_vector_type(8))) short bf16x8;
typedef __attribute__((ext_vector_type(4))) float f32x4;
typedef uint32_t u32;
typedef unsigned short ushort_t;

// ---- static device scratch ----
__device__ float g_F1[(size_t)NVERT * EDIM];
__device__ float g_F2[(size_t)NVERT * EDIM];
__device__ float g_F3[(size_t)NVERT * EDIM];
__device__ float g_S0[(size_t)NVERT * EDIM];
__device__ float g_h1[(size_t)BATCHC * 64];
__device__ ushort_t g_wb[3 * 4 * EDIM * EDIM];
__device__ ushort_t g_w1b[2 * 64 * 1024];
__device__ int   g_row_ptr[NVERT + 1];
__device__ int   g_cnt[NVERT];
__device__ int   g_col_s[NNZC];
__device__ float g_val_s[NNZC];
__device__ int   g_bsums[1024];

// ---- bf16 helpers ----
__device__ inline u32 f2bf(float f) {  // RNE
  u32 u = __float_as_uint(f);
  return (u + 0x7FFFu + ((u >> 16) & 1u)) >> 16;
}
__device__ inline void split_bf(float x, u32& hi16, float& lo) {
  u32 u = __float_as_uint(x);
  u32 hb = (u + 0x7FFFu + ((u >> 16) & 1u)) & 0xFFFF0000u;
  hi16 = hb >> 16;
  lo = x - __uint_as_float(hb);
}

// ---------------- utility ----------------
__global__ __launch_bounds__(256) void k_zero(int* __restrict__ p, int n) {
  int i = blockIdx.x * 256 + threadIdx.x;
  if (i < n) p[i] = 0;
}

// ---------------- CSR build ----------------
__global__ __launch_bounds__(256) void k_hist(const int* __restrict__ rows, int* __restrict__ cnt) {
  int i = blockIdx.x * 256 + threadIdx.x;
  if (i < NNZC) atomicAdd(&cnt[rows[i]], 1);
}

__device__ inline int wave_iscan(int v, int lane) {
#pragma unroll
  for (int off = 1; off < 64; off <<= 1) {
    int u = __shfl_up(v, off, 64);
    if (lane >= off) v += u;
  }
  return v;
}

__global__ __launch_bounds__(256) void k_scan1(const int* __restrict__ cnt, int* __restrict__ excl,
                                               int* __restrict__ bsums) {
  int t = threadIdx.x, gid = blockIdx.x * 256 + t;
  int lane = t & 63, w = t >> 6;
  int v = (gid < NVERT) ? cnt[gid] : 0;
  int s = wave_iscan(v, lane);
  __shared__ int ws4[4];
  if (lane == 63) ws4[w] = s;
  __syncthreads();
  int add = 0;
  for (int i = 0; i < w; ++i) add += ws4[i];
  if (gid < NVERT) excl[gid] = s + add - v;
  if (t == 255) bsums[blockIdx.x] = s + add;
}

__global__ __launch_bounds__(1024) void k_scan2(int* __restrict__ bsums, int nb) {
  int t = threadIdx.x;
  int lane = t & 63, w = t >> 6;
  int v = (t < nb) ? bsums[t] : 0;
  int s = wave_iscan(v, lane);
  __shared__ int ws16[16];
  if (lane == 63) ws16[w] = s;
  __syncthreads();
  int add = 0;
  for (int i = 0; i < w; ++i) add += ws16[i];
  if (t < nb) bsums[t] = s + add - v;
}

__global__ __launch_bounds__(256) void k_scan3(int* __restrict__ excl, const int* __restrict__ bsums,
                                               int* __restrict__ cursor) {
  int gid = blockIdx.x * 256 + threadIdx.x;
  if (gid < NVERT) {
    int v = excl[gid] + bsums[blockIdx.x];
    excl[gid] = v;
    cursor[gid] = v;
  }
  if (gid == 0) excl[NVERT] = NNZC;
}

__global__ __launch_bounds__(256) void k_scatter(const int* __restrict__ rows, const int* __restrict__ cols,
                                                 const float* __restrict__ vals, int* __restrict__ cursor,
                                                 int* __restrict__ col_s, float* __restrict__ val_s) {
  int i = blockIdx.x * 256 + threadIdx.x;
  if (i < NNZC) {
    int r = rows[i];
    int p = atomicAdd(&cursor[r], 1);
    col_s[p] = cols[i];
    val_s[p] = vals[i];
  }
}

// ---------------- weight hi/lo split: per layer {Whi, Wlo, IWhi, IWlo} ----------------
__global__ __launch_bounds__(256) void k_cvtW(const float* __restrict__ w, const float* __restrict__ iw,
                                              ushort_t* __restrict__ wb) {
  int i = blockIdx.x * 256 + threadIdx.x;
  if (i >= 2 * 3 * 16384) return;
  int m = i >= 3 * 16384;
  int j = i - m * 3 * 16384;
  int l = j >> 14, e = j & 16383;
  float x = m ? iw[j] : w[j];
  u32 h;
  float lo;
  split_bf(x, h, lo);
  size_t base = (size_t)l * 65536 + (size_t)m * 32768;
  wb[base + e] = (ushort_t)h;
  wb[base + 16384 + e] = (ushort_t)f2bf(lo);
}

// ---------------- t1_w hi/lo split ----------------
__global__ __launch_bounds__(256) void k_cvtW1(const float* __restrict__ w1, ushort_t* __restrict__ w1b) {
  int i = blockIdx.x * 256 + threadIdx.x;
  if (i >= 64 * 1024) return;
  u32 h;
  float lo;
  split_bf(w1[i], h, lo);
  w1b[i] = (ushort_t)h;
  w1b[65536 + i] = (ushort_t)f2bf(lo);
}

// ---------------- MFMA dual GEMM: ZX = X@W^T ; S0 = ZX + (X*X)@IW^T ----------------
// single-pass dual accumulator; weights LDS-staged (2 K-half phases);
// transpose epilogue via per-wave private 8KB swizzled tiles.
// ZX is written into the LAYER OUTPUT buffer (spmm2 finalizes it in place) -> no Z1 buffer,
// smaller L3 footprint so the S0 gather stays resident.
__global__ __launch_bounds__(512, 2) void k_gemmZb(
    const float* __restrict__ Xu, const float* __restrict__ Xi, const ushort_t* __restrict__ wb,
    float* __restrict__ S0, float* __restrict__ ZX) {
  __shared__ ushort_t sw[4 * 128 * 64];  // 64 KB (weights; reused as 8x8KB epilogue tiles)
  int t = threadIdx.x;
  int w = t >> 6, lane = t & 63;
  int row0 = blockIdx.x * 256 + w * 32;
  int lr = lane & 15;
  int kg = lane >> 4;
  int kofs = kg * 8;

  f32x4 accZ[2][8], accQ[2][8];
#pragma unroll
  for (int i = 0; i < 2; ++i)
#pragma unroll
    for (int j = 0; j < 8; ++j) { accZ[i][j] = (f32x4)0.f; accQ[i][j] = (f32x4)0.f; }

  union U8 { u32 u[4]; bf16x8 v; };

  for (int ph = 0; ph < 2; ++ph) {
    __syncthreads();
#pragma unroll
    for (int i = 0; i < 8; ++i) {
      int c = i * 512 + t;
      int mat = c >> 10;
      int rem = c & 1023;
      int row = rem >> 3;
      int cb = (rem & 7) * 16;
      const ushort_t* src = wb + mat * 16384 + row * 128 + ph * 64 + (cb >> 1);
      float4 v = *(const float4*)src;
      int swz = cb ^ ((row & 7) << 4);
      *(float4*)((char*)sw + mat * 16384 + row * 128 + swz) = v;
    }
    __syncthreads();

#pragma unroll
    for (int k0l = 0; k0l < 64; k0l += 32) {
      int kglob = ph * 64 + k0l + kofs;
      bf16x8 fxh[2], fxl[2], fqh[2], fql[2];
#pragma unroll
      for (int rf = 0; rf < 2; ++rf) {
        int row = row0 + rf * 16 + lr;
        float xv[8];
        if (row < NVERT) {
          const float* xbase = (row < UN) ? (Xu + (size_t)row * EDIM)
                                          : (Xi + (size_t)(row - UN) * EDIM);
          const float4* xp = (const float4*)(xbase + kglob);
          float4 x0 = xp[0], x1 = xp[1];
          xv[0] = x0.x; xv[1] = x0.y; xv[2] = x0.z; xv[3] = x0.w;
          xv[4] = x1.x; xv[5] = x1.y; xv[6] = x1.z; xv[7] = x1.w;
        } else {
#pragma unroll
          for (int q = 0; q < 8; ++q) xv[q] = 0.f;
        }
        U8 xh, xl, qh, ql;
        u32 h0, h1;
        float l0, l1;
#pragma unroll
        for (int p = 0; p < 4; ++p) {
          split_bf(xv[2 * p], h0, l0);
          split_bf(xv[2 * p + 1], h1, l1);
          xh.u[p] = h0 | (h1 << 16);
          xl.u[p] = f2bf(l0) | (f2bf(l1) << 16);
          float q0 = xv[2 * p] * xv[2 * p];
          float q1 = xv[2 * p + 1] * xv[2 * p + 1];
          split_bf(q0, h0, l0);
          split_bf(q1, h1, l1);
          qh.u[p] = h0 | (h1 << 16);
          ql.u[p] = f2bf(l0) | (f2bf(l1) << 16);
        }
        fxh[rf] = xh.v; fxl[rf] = xl.v; fqh[rf] = qh.v; fql[rf] = ql.v;
      }
      int cswz = (k0l * 2 + kg * 16) ^ ((lr & 7) << 4);
#pragma unroll
      for (int cf = 0; cf < 8; ++cf) {
        int rb = (cf * 16 + lr) * 128 + cswz;
        bf16x8 wh = *(const bf16x8*)((const char*)sw + rb);
        bf16x8 wl = *(const bf16x8*)((const char*)sw + 16384 + rb);
        bf16x8 ih = *(const bf16x8*)((const char*)sw + 32768 + rb);
        bf16x8 il = *(const bf16x8*)((const char*)sw + 49152 + rb);
#pragma unroll
        for (int rf = 0; rf < 2; ++rf) {
          accZ[rf][cf] = __builtin_amdgcn_mfma_f32_16x16x32_bf16(fxh[rf], wh, accZ[rf][cf], 0, 0, 0);
          accZ[rf][cf] = __builtin_amdgcn_mfma_f32_16x16x32_bf16(fxl[rf], wh, accZ[rf][cf], 0, 0, 0);
          accZ[rf][cf] = __builtin_amdgcn_mfma_f32_16x16x32_bf16(fxh[rf], wl, accZ[rf][cf], 0, 0, 0);
          accQ[rf][cf] = __builtin_amdgcn_mfma_f32_16x16x32_bf16(fqh[rf], ih, accQ[rf][cf], 0, 0, 0);
          accQ[rf][cf] = __builtin_amdgcn_mfma_f32_16x16x32_bf16(fql[rf], ih, accQ[rf][cf], 0, 0, 0);
          accQ[rf][cf] = __builtin_amdgcn_mfma_f32_16x16x32_bf16(fqh[rf], il, accQ[rf][cf], 0, 0, 0);
        }
      }
    }
  }

  // ---- epilogue: per-wave private LDS transpose -> coalesced float4 stores ----
  __syncthreads();  // all waves done reading weights before tiles overwrite them
  char* ep = (char*)sw + w * 8192;  // 16 rows x 512 B, XOR-swizzled
#pragma unroll
  for (int rf = 0; rf < 2; ++rf) {
#pragma unroll
    for (int mat = 0; mat < 2; ++mat) {
#pragma unroll
      for (int cf = 0; cf < 8; ++cf) {
        int col = cf * 16 + lr;
#pragma unroll
        for (int r = 0; r < 4; ++r) {
          int row = kg * 4 + r;
          float v = (mat == 0) ? (accZ[rf][cf][r] + accQ[rf][cf][r]) : accZ[rf][cf][r];
          *(float*)(ep + row * 512 + ((col * 4) ^ ((row & 7) << 4))) = v;
        }
      }
      float* dst = (mat == 0) ? S0 : ZX;
#pragma unroll
      for (int it = 0; it < 8; ++it) {
        int row2 = it * 2 + (lane >> 5);
        int gr = row0 + rf * 16 + row2;
        float4 v4 = *(float4*)(ep + row2 * 512 + (((lane & 31) * 16) ^ ((row2 & 7) << 4)));
        if (gr < NVERT) *(float4*)&dst[(size_t)gr * EDIM + (lane & 31) * 4] = v4;
      }
    }
  }
}

// ---------------- SpMM finalize (in place): ZX = leaky(L@S0 + ZX + b + ib) ----------------
__global__ __launch_bounds__(256) void k_spmm2(
    const int* __restrict__ rp, const int* __restrict__ cs, const float* __restrict__ vs,
    const float* __restrict__ S0, float* __restrict__ ZX,
    const float* __restrict__ gb, const float* __restrict__ gib) {
  int lane = threadIdx.x & 63;
  int row = (blockIdx.x * 4 + (threadIdx.x >> 6)) * 2 + (lane >> 5);
  if (row >= NVERT) return;
  int c4 = (lane & 31) * 4;
  int beg = rp[row], end = rp[row + 1];
  float ax = 0.f, ay = 0.f, az = 0.f, aw = 0.f;
  for (int j = beg; j < end; j += 4) {
    int lim = end - 1;
    int j1 = j + 1 <= lim ? j + 1 : lim;
    int j2 = j + 2 <= lim ? j + 2 : lim;
    int j3 = j + 3 <= lim ? j + 3 : lim;
    int c0 = cs[j], c1 = cs[j1], c2 = cs[j2], c3 = cs[j3];
    float v0 = vs[j];
    float v1 = (j + 1 <= lim) ? vs[j1] : 0.f;
    float v2 = (j + 2 <= lim) ? vs[j2] : 0.f;
    float v3 = (j + 3 <= lim) ? vs[j3] : 0.f;
    float4 g0 = *(const float4*)&S0[(size_t)c0 * EDIM + c4];
    float4 g1 = *(const float4*)&S0[(size_t)c1 * EDIM + c4];
    float4 g2 = *(const float4*)&S0[(size_t)c2 * EDIM + c4];
    float4 g3 = *(const float4*)&S0[(size_t)c3 * EDIM + c4];
    ax = fmaf(v0, g0.x, ax); ay = fmaf(v0, g0.y, ay); az = fmaf(v0, g0.z, az); aw = fmaf(v0, g0.w, aw);
    ax = fmaf(v1, g1.x, ax); ay = fmaf(v1, g1.y, ay); az = fmaf(v1, g1.z, az); aw = fmaf(v1, g1.w, aw);
    ax = fmaf(v2, g2.x, ax); ay = fmaf(v2, g2.y, ay); az = fmaf(v2, g2.z, az); aw = fmaf(v2, g2.w, aw);
    ax = fmaf(v3, g3.x, ax); ay = fmaf(v3, g3.y, ay); az = fmaf(v3, g3.z, az); aw = fmaf(v3, g3.w, aw);
  }
  float* zp = &ZX[(size_t)row * EDIM + c4];
  float4 z = *(const float4*)zp;
  float4 b1 = *(const float4*)&gb[c4];
  float4 b2 = *(const float4*)&gib[c4];
  float o0 = ax + z.x + b1.x + b2.x;
  float o1 = ay + z.y + b1.y + b2.y;
  float o2 = az + z.z + b1.z + b2.z;
  float o3 = aw + z.w + b1.w + b2.w;
  o0 = o0 > 0.f ? o0 : 0.01f * o0;
  o1 = o1 > 0.f ? o1 : 0.01f * o1;
  o2 = o2 > 0.f ? o2 : 0.01f * o2;
  o3 = o3 > 0.f ? o3 : 0.01f * o3;
  *(float4*)zp = make_float4(o0, o1, o2, o3);
}

// ---------------- final t1: h1 = gather(embd,F1..3)[u,i] @ t1_w^T + b1 ----------------
__global__ __launch_bounds__(256) void k_t1b(
    const float* __restrict__ Eu, const float* __restrict__ Ei,
    const float* __restrict__ F1, const float* __restrict__ F2, const float* __restrict__ F3,
    const int* __restrict__ ui, const int* __restrict__ ii,
    const ushort_t* __restrict__ w1b, const float* __restrict__ b1,
    float* __restrict__ h1) {
  __shared__ ushort_t sw1[2 * 64 * 128];  // 32 KB: hi block, lo block
  int t = threadIdx.x;
  int w = t >> 6, lane = t & 63;
  int b0 = blockIdx.x * 128 + w * 32;
  int lr = lane & 15, kg = lane >> 4, kofs = kg * 8;

  int uidx[2], iidx[2];
#pragma unroll
  for (int rf = 0; rf < 2; ++rf) {
    int b = b0 + rf * 16 + lr;
    uidx[rf] = ui[b];
    iidx[rf] = ii[b];
  }

  f32x4 acc[2][4];
#pragma unroll
  for (int i = 0; i < 2; ++i)
#pragma unroll
    for (int j = 0; j < 4; ++j) acc[i][j] = (f32x4)0.f;

  union U8 { u32 u[4]; bf16x8 v; };

#pragma unroll
  for (int slot = 0; slot < 8; ++slot) {
    __syncthreads();
#pragma unroll
    for (int i = 0; i < 8; ++i) {
      int c = i * 256 + t;
      int comp = c >> 10;
      int rem = c & 1023;
      int row = rem >> 4;
      int cb = (rem & 15) * 16;
      const ushort_t* src = w1b + comp * 65536 + row * 1024 + slot * 128 + (cb >> 1);
      float4 v = *(const float4*)src;
      *(float4*)((char*)sw1 + comp * 16384 + row * 256 + (cb ^ ((row & 7) << 4))) = v;
    }
    __syncthreads();

    int side = slot >> 2, layer = slot & 3;
    const float* Fl = (layer == 0) ? (side ? Ei : Eu)
                    : (layer == 1) ? F1 : (layer == 2) ? F2 : F3;
    int radd = (side && layer != 0) ? UN : 0;

#pragma unroll
    for (int kk = 0; kk < 4; ++kk) {
      bf16x8 fxh[2], fxl[2];
#pragma unroll
      for (int rf = 0; rf < 2; ++rf) {
        int ridx = (side ? iidx[rf] : uidx[rf]) + radd;
        const float4* xp = (const float4*)(Fl + (size_t)ridx * EDIM + kk * 32 + kofs);
        float4 x0 = xp[0], x1 = xp[1];
        float xv[8] = {x0.x, x0.y, x0.z, x0.w, x1.x, x1.y, x1.z, x1.w};
        U8 xh, xl;
        u32 h0, h1;
        float l0, l1;
#pragma unroll
        for (int p = 0; p < 4; ++p) {
          split_bf(xv[2 * p], h0, l0);
          split_bf(xv[2 * p + 1], h1, l1);
          xh.u[p] = h0 | (h1 << 16);
          xl.u[p] = f2bf(l0) | (f2bf(l1) << 16);
        }
        fxh[rf] = xh.v;
        fxl[rf] = xl.v;
      }
      int cbyte = (kk * 64 + kg * 16) ^ ((lr & 7) << 4);
#pragma unroll
      for (int cf = 0; cf < 4; ++cf) {
        int rb = (cf * 16 + lr) * 256 + cbyte;
        bf16x8 wh = *(const bf16x8*)((const char*)sw1 + rb);
        bf16x8 wl = *(const bf16x8*)((const char*)sw1 + 16384 + rb);
#pragma unroll
        for (int rf = 0; rf < 2; ++rf) {
          acc[rf][cf] = __builtin_amdgcn_mfma_f32_16x16x32_bf16(fxh[rf], wh, acc[rf][cf], 0, 0, 0);
          acc[rf][cf] = __builtin_amdgcn_mfma_f32_16x16x32_bf16(fxl[rf], wh, acc[rf][cf], 0, 0, 0);
          acc[rf][cf] = __builtin_amdgcn_mfma_f32_16x16x32_bf16(fxh[rf], wl, acc[rf][cf], 0, 0, 0);
        }
      }
    }
  }
#pragma unroll
  for (int rf = 0; rf < 2; ++rf) {
    int rbase = b0 + rf * 16 + ((lane >> 4) << 2);
#pragma unroll
    for (int cf = 0; cf < 4; ++cf) {
      int col = cf * 16 + lr;
      float bv = b1[col];
#pragma unroll
      for (int r = 0; r < 4; ++r) {
        h1[(size_t)(rbase + r) * 64 + col] = acc[rf][cf][r] + bv;
      }
    }
  }
}

// ---------------- fused t2 + t3 (h1 holds pre-ReLU t1 output) ----------------
__global__ __launch_bounds__(256) void k_tail(const float* __restrict__ h1, const float* __restrict__ w2,
                                              const float* __restrict__ b2, const float* __restrict__ w3,
                                              const float* __restrict__ b3, float* __restrict__ out) {
  __shared__ float w2s[32][65];
  __shared__ float w3s[32];
  int t = threadIdx.x;
  for (int i = t; i < 32 * 64; i += 256) w2s[i >> 6][i & 63] = w2[i];
  if (t < 32) w3s[t] = w3[t];
  __syncthreads();
  int b = blockIdx.x * 8 + (t >> 5);
  int j = t & 31;
  const float* hr = h1 + (size_t)b * 64;
  float acc = b2[j];
#pragma unroll 8
  for (int k = 0; k < 64; ++k) {
    float hv = fmaxf(hr[k], 0.f);
    acc = fmaf(hv, w2s[j][k], acc);
  }
  acc = fmaxf(acc, 0.f);
  float p = acc * w3s[j];
#pragma unroll
  for (int off = 16; off > 0; off >>= 1) p += __shfl_xor(p, off, 64);
  if (j == 0) out[b] = p + b3[0];
}

// ---------------- launcher ----------------
extern "C" void kernel_launch(void* const* d_in, const int* in_sizes, int n_in,
                              void* d_out, int out_size, void* d_ws, size_t ws_size,
                              hipStream_t stream) {
  const int* user_idx = (const int*)d_in[0];
  const int* item_idx = (const int*)d_in[1];
  const int* rows = (const int*)d_in[2];
  const int* cols = (const int*)d_in[3];
  const float* vals = (const float*)d_in[4];
  const float* u_embd = (const float*)d_in[5];
  const float* i_embd = (const float*)d_in[6];
  const float* gnn_w = (const float*)d_in[7];
  const float* gnn_b = (const float*)d_in[8];
  const float* gnn_iw = (const float*)d_in[9];
  const float* gnn_ib = (const float*)d_in[10];
  const float* t1_w = (const float*)d_in[11];
  const float* t1_b = (const float*)d_in[12];
  const float* t2_w = (const float*)d_in[13];
  const float* t2_b = (const float*)d_in[14];
  const float* t3_w = (const float*)d_in[15];
  const float* t3_b = (const float*)d_in[16];
  float* out = (float*)d_out;
  (void)d_ws; (void)ws_size; (void)in_sizes; (void)n_in; (void)out_size;

  float *F1, *F2, *F3, *S0, *h1, *val_s;
  ushort_t *wb, *w1b;
  int *row_ptr, *cnt, *col_s, *bsums;
  (void)hipGetSymbolAddress((void**)&F1, HIP_SYMBOL(g_F1));
  (void)hipGetSymbolAddress((void**)&F2, HIP_SYMBOL(g_F2));
  (void)hipGetSymbolAddress((void**)&F3, HIP_SYMBOL(g_F3));
  (void)hipGetSymbolAddress((void**)&S0, HIP_SYMBOL(g_S0));
  (void)hipGetSymbolAddress((void**)&h1, HIP_SYMBOL(g_h1));
  (void)hipGetSymbolAddress((void**)&wb, HIP_SYMBOL(g_wb));
  (void)hipGetSymbolAddress((void**)&w1b, HIP_SYMBOL(g_w1b));
  (void)hipGetSymbolAddress((void**)&row_ptr, HIP_SYMBOL(g_row_ptr));
  (void)hipGetSymbolAddress((void**)&cnt, HIP_SYMBOL(g_cnt));
  (void)hipGetSymbolAddress((void**)&col_s, HIP_SYMBOL(g_col_s));
  (void)hipGetSymbolAddress((void**)&val_s, HIP_SYMBOL(g_val_s));
  (void)hipGetSymbolAddress((void**)&bsums, HIP_SYMBOL(g_bsums));

  int nbV = (NVERT + 255) / 256;  // 586
  k_zero<<<nbV, 256, 0, stream>>>(cnt, NVERT);
  k_hist<<<(NNZC + 255) / 256, 256, 0, stream>>>(rows, cnt);
  k_scan1<<<nbV, 256, 0, stream>>>(cnt, row_ptr, bsums);
  k_scan2<<<1, 1024, 0, stream>>>(bsums, nbV);
  k_scan3<<<nbV, 256, 0, stream>>>(row_ptr, bsums, cnt);  // cnt becomes cursor
  k_scatter<<<(NNZC + 255) / 256, 256, 0, stream>>>(rows, cols, vals, cnt, col_s, val_s);
  k_cvtW<<<(2 * 3 * 16384 + 255) / 256, 256, 0, stream>>>(gnn_w, gnn_iw, wb);
  k_cvtW1<<<(64 * 1024 + 255) / 256, 256, 0, stream>>>(t1_w, w1b);

  int nbG = (NVERT + 255) / 256;  // 586
  int nbS = (NVERT + 7) / 8;      // 18750
  float* fouts[3] = {F1, F2, F3};
  const float* cu = u_embd;
  const float* ci = i_embd;
  for (int l = 0; l < 3; ++l) {
    k_gemmZb<<<nbG, 512, 0, stream>>>(cu, ci, wb + (size_t)l * 65536, S0, fouts[l]);
    k_spmm2<<<nbS, 256, 0, stream>>>(row_ptr, col_s, val_s, S0, fouts[l],
                                     gnn_b + (size_t)l * EDIM, gnn_ib + (size_t)l * EDIM);
    cu = fouts[l];
    ci = fouts[l] + (size_t)UN * EDIM;
  }
  k_t1b<<<BATCHC / 128, 256, 0, stream>>>(u_embd, i_embd, F1, F2, F3,
                                          user_idx, item_idx, w1b, t1_b, h1);
  k_tail<<<BATCHC / 8, 256, 0, stream>>>(h1, t2_w, t2_b, t3_w, t3_b, out);
}